// Round 8
// baseline (256.672 us; speedup 1.0000x reference)
//
#include <hip/hip_runtime.h>
#include <hip/hip_bf16.h>

typedef __attribute__((ext_vector_type(8))) short short8;
typedef __attribute__((ext_vector_type(4))) float f32x4;
typedef __attribute__((ext_vector_type(16))) float f32x16;

__device__ __forceinline__ unsigned short f32_bf16(float f) {
  unsigned u = __float_as_uint(f);
  u += 0x7fffu + ((u >> 16) & 1u);  // round-to-nearest-even
  return (unsigned short)(u >> 16);
}

__device__ __forceinline__ short8 cvt8(float4 v0, float4 v1) {
  short8 f;
  f[0] = (short)f32_bf16(v0.x); f[1] = (short)f32_bf16(v0.y);
  f[2] = (short)f32_bf16(v0.z); f[3] = (short)f32_bf16(v0.w);
  f[4] = (short)f32_bf16(v1.x); f[5] = (short)f32_bf16(v1.y);
  f[6] = (short)f32_bf16(v1.z); f[7] = (short)f32_bf16(v1.w);
  return f;
}

// DPP row_shr:N add — VALU-pipe cross-lane. After shr8,4,2,1 lane 15 of each
// 16-lane row holds the row sum.
template <int CTRL>
__device__ __forceinline__ float dpp_add(float x) {
  int y = __builtin_amdgcn_update_dpp(0, __float_as_int(x), CTRL, 0xf, 0xf, true);
  return x + __int_as_float(y);
}
__device__ __forceinline__ float row_sum16(float x) {
  x = dpp_add<0x118>(x);
  x = dpp_add<0x114>(x);
  x = dpp_add<0x112>(x);
  x = dpp_add<0x111>(x);
  return x;
}

// ---- pass 1: z (fp32) -> z_bf16 in workspace --------------------------------
__global__ __launch_bounds__(256) void cvt_bf16_kernel(const float* __restrict__ z,
                                                       unsigned short* __restrict__ zb,
                                                       int n) {
  int i = (blockIdx.x * 256 + threadIdx.x) * 8;
  if (i + 8 <= n) {
    float4 v0 = *(const float4*)(z + i);
    float4 v1 = *(const float4*)(z + i + 4);
    union { unsigned short us[8]; uint4 u4; } r;
    r.us[0] = f32_bf16(v0.x); r.us[1] = f32_bf16(v0.y);
    r.us[2] = f32_bf16(v0.z); r.us[3] = f32_bf16(v0.w);
    r.us[4] = f32_bf16(v1.x); r.us[5] = f32_bf16(v1.y);
    r.us[6] = f32_bf16(v1.z); r.us[7] = f32_bf16(v1.w);
    *(uint4*)(zb + i) = r.u4;
  }
}

// ---- pass 2: fused gather + 3-layer MLP + sigmoid ---------------------------
// Diagnosis R1-R7: wall time == FETCH/~2.2 TB/s — the random-gather L2-miss
// path is the limiter (latency x outstanding-lines, not pipe throughput).
// R8 maximizes residency + in-flight lines:
//  - LDS exactly 40960 B (W1 frags 32 KB + h1 8 KB; W2 frags in persistent
//    registers) -> 4 blocks/CU; grid 1024 = exact 4/CU, persistent.
//  - all 16 gather b128s issue in one window (no sched_barrier); ~116 arch
//    regs < the measured 128 arch wall (R2/R3/R4/R6 spilled above it).
//  - h1: packed 2 bf16/dword, stride 32 dwords, XOR swizzle
//    col' = (col + 4*(row&7)) & 31 -> conflict-free b32 writes + b128 reads.
// Layer 1: mfma_f32_32x32x16_bf16, M=32 edges, N=64 (2 ntiles, col slot
// (t,col) = feature 2*col+t), K=256 (16 chunks). A[m=lane&31][k=(lane>>5)*8+j];
// C/D row = (reg&3)+8*(reg>>2)+4*(lane>>5) (verified R7 pass).
// Layer 2: 16x16x32 on two 16-edge halves (verified R5 path). Layer 3: DPP.
template <bool ZBF>
__global__ __launch_bounds__(256, 2) void lp_main(
    const float* __restrict__ zf, const unsigned short* __restrict__ zb,
    const int* __restrict__ ei,
    const float* __restrict__ W1, const float* __restrict__ b1,
    const float* __restrict__ W2, const float* __restrict__ b2,
    const float* __restrict__ W3, const float* __restrict__ b3,
    float* __restrict__ out, int nEdges) {
  __shared__ unsigned short w1l[32 * 64 * 8];          // 32768 B
  __shared__ __align__(16) unsigned h1d[4][16 * 32];   // 8192 B (dword-packed)

  const int tid = threadIdx.x;
  const int wv  = tid >> 6;
  const int l   = tid & 63;
  const int l15 = l & 15;
  const int q   = l >> 4;
  const int e32 = l & 31;   // edge-in-tile for 32x32 A/C
  const int hb  = l >> 5;   // k-half for 32x32 A/B

  // ---- stage W1 B-fragments (32x32x16): frag p = c*2 + t ----
  // slot (t, col=e32) computes original feature 2*e32 + t.
#pragma unroll
  for (int pp = 0; pp < 8; ++pp) {
    int p = wv * 8 + pp;
    int c = p >> 1, t = p & 1;
    short8 f;
#pragma unroll
    for (int j = 0; j < 8; ++j)
      f[j] = (short)f32_bf16(W1[(c * 16 + hb * 8 + j) * 64 + ((e32 << 1) | t)]);
    *(short8*)(w1l + (p * 64 + l) * 8) = f;
  }

  // ---- W2 B-fragments (16x16x32) in persistent registers ----
  short8 w2f[2][2];
#pragma unroll
  for (int c2 = 0; c2 < 2; ++c2)
#pragma unroll
    for (int t2 = 0; t2 < 2; ++t2) {
      short8 f;
#pragma unroll
      for (int j = 0; j < 8; ++j)
        f[j] = (short)f32_bf16(W2[(c2 * 32 + q * 8 + j) * 32 + (t2 * 16 + l15)]);
      w2f[c2][t2] = f;
    }

  float bb1[2];
#pragma unroll
  for (int t = 0; t < 2; ++t) bb1[t] = b1[(e32 << 1) | t];
  float bb2[2];
#pragma unroll
  for (int t = 0; t < 2; ++t) bb2[t] = b2[t * 16 + l15];
  const float w3a = W3[l15], w3b = W3[16 + l15], b3v = b3[0];

  __syncthreads();

  unsigned* h1p = h1d[wv];

  const int nIter = (nEdges + 31) >> 5;
  const int stride = gridDim.x * 4;
  int iter = blockIdx.x * 4 + wv;

  int cS = 0, cD = 0;
  if (iter < nIter) {
    int e = iter * 32 + e32;
    e = e < nEdges ? e : nEdges - 1;
    cS = ei[e];
    cD = ei[nEdges + e];
  }

  for (; iter < nIter; iter += stride) {
    // ---- gather: all 16 b128 loads issue in one window ----
    short8 as[8], ad[8];
    if (ZBF) {
      const unsigned short* rs = zb + (size_t)cS * 128;
      const unsigned short* rd = zb + (size_t)cD * 128;
#pragma unroll
      for (int c = 0; c < 8; ++c) {
        as[c] = *(const short8*)(rs + c * 16 + hb * 8);
        ad[c] = *(const short8*)(rd + c * 16 + hb * 8);
      }
    } else {
      const float* rs = zf + (size_t)cS * 128;
      const float* rd = zf + (size_t)cD * 128;
#pragma unroll
      for (int c = 0; c < 8; ++c) {
        int off = c * 16 + hb * 8;
        as[c] = cvt8(*(const float4*)(rs + off), *(const float4*)(rs + off + 4));
        ad[c] = cvt8(*(const float4*)(rd + off), *(const float4*)(rd + off + 4));
      }
    }

    // prefetch next iteration's edge indices
    int nit = iter + stride;
    int nS = cS, nD = cD;
    if (nit < nIter) {
      int e = nit * 32 + e32;
      e = e < nEdges ? e : nEdges - 1;
      nS = ei[e];
      nD = ei[nEdges + e];
    }

    // ---- layer 1: [32,256] @ [256,64], 32x32x16 ----
    f32x16 acc[2];
#pragma unroll
    for (int t = 0; t < 2; ++t)
#pragma unroll
      for (int i = 0; i < 16; ++i) acc[t][i] = bb1[t];

#pragma unroll
    for (int c = 0; c < 8; ++c) {
      short8 w0 = *(const short8*)(w1l + ((c * 2 + 0) * 64 + l) * 8);
      acc[0] = __builtin_amdgcn_mfma_f32_32x32x16_bf16(as[c], w0, acc[0], 0, 0, 0);
      short8 w1f = *(const short8*)(w1l + ((c * 2 + 1) * 64 + l) * 8);
      acc[1] = __builtin_amdgcn_mfma_f32_32x32x16_bf16(as[c], w1f, acc[1], 0, 0, 0);
    }
#pragma unroll
    for (int c = 0; c < 8; ++c) {
      short8 w0 = *(const short8*)(w1l + (((c + 8) * 2 + 0) * 64 + l) * 8);
      acc[0] = __builtin_amdgcn_mfma_f32_32x32x16_bf16(ad[c], w0, acc[0], 0, 0, 0);
      short8 w1f = *(const short8*)(w1l + (((c + 8) * 2 + 1) * 64 + l) * 8);
      acc[1] = __builtin_amdgcn_mfma_f32_32x32x16_bf16(ad[c], w1f, acc[1], 0, 0, 0);
    }

    // ---- per 16-edge half: h1 write -> layer2 -> layer3 -> store ----
#pragma unroll
    for (int T = 0; T < 2; ++T) {
      // relu + pack feats (2*e32, 2*e32+1) -> one swizzled b32 per row-reg
#pragma unroll
      for (int rr = 0; rr < 8; ++rr) {
        int r = T * 8 + rr;
        int er = (rr & 3) + 8 * (rr >> 2) + 4 * hb;        // local row 0..15
        int colw = (e32 + ((er & 7) << 2)) & 31;           // XOR-rot swizzle
        float v0 = acc[0][r]; v0 = v0 > 0.f ? v0 : 0.f;
        float v1 = acc[1][r]; v1 = v1 > 0.f ? v1 : 0.f;
        unsigned u = ((unsigned)f32_bf16(v1) << 16) | f32_bf16(v0);
        h1p[er * 32 + colw] = u;
      }

      // layer 2: [16,64] @ [64,32], 16x16x32; swizzled b128 reads
      int rot = (l15 & 7) << 2;
      short8 a2_0 = *(const short8*)(h1p + l15 * 32 + ((q * 4 + rot) & 31));
      short8 a2_1 = *(const short8*)(h1p + l15 * 32 + ((q * 4 + 16 + rot) & 31));

      f32x4 acc2[2];
#pragma unroll
      for (int t2 = 0; t2 < 2; ++t2) {
        acc2[t2][0] = bb2[t2]; acc2[t2][1] = bb2[t2];
        acc2[t2][2] = bb2[t2]; acc2[t2][3] = bb2[t2];
      }
#pragma unroll
      for (int t2 = 0; t2 < 2; ++t2) {
        acc2[t2] = __builtin_amdgcn_mfma_f32_16x16x32_bf16(a2_0, w2f[0][t2], acc2[t2], 0, 0, 0);
        acc2[t2] = __builtin_amdgcn_mfma_f32_16x16x32_bf16(a2_1, w2f[1][t2], acc2[t2], 0, 0, 0);
      }

      // layer 3: per-lane partial, DPP row-sum (VALU pipe)
      float p[4];
#pragma unroll
      for (int r2 = 0; r2 < 4; ++r2) {
        float h0 = acc2[0][r2]; h0 = h0 > 0.f ? h0 : 0.f;
        float h1v = acc2[1][r2]; h1v = h1v > 0.f ? h1v : 0.f;
        p[r2] = row_sum16(h0 * w3a + h1v * w3b);
      }

      if (l15 == 15) {
        int eb = iter * 32 + T * 16 + q * 4;
        float4 o;
        o.x = 1.f / (1.f + __expf(-(p[0] + b3v)));
        o.y = 1.f / (1.f + __expf(-(p[1] + b3v)));
        o.z = 1.f / (1.f + __expf(-(p[2] + b3v)));
        o.w = 1.f / (1.f + __expf(-(p[3] + b3v)));
        if (eb + 3 < nEdges) {
          *(float4*)(out + eb) = o;
        } else {
          if (eb < nEdges)     out[eb]     = o.x;
          if (eb + 1 < nEdges) out[eb + 1] = o.y;
          if (eb + 2 < nEdges) out[eb + 2] = o.z;
        }
      }
    }

    cS = nS; cD = nD;
  }
}

extern "C" void kernel_launch(void* const* d_in, const int* in_sizes, int n_in,
                              void* d_out, int out_size, void* d_ws, size_t ws_size,
                              hipStream_t stream) {
  const float* z  = (const float*)d_in[0];
  const int* ei   = (const int*)d_in[1];
  const float* W1 = (const float*)d_in[2];
  const float* b1 = (const float*)d_in[3];
  const float* W2 = (const float*)d_in[4];
  const float* b2 = (const float*)d_in[5];
  const float* W3 = (const float*)d_in[6];
  const float* b3 = (const float*)d_in[7];
  float* out = (float*)d_out;

  const int nZ = in_sizes[0];
  const int nEdges = in_sizes[1] / 2;

  const bool useWs = ws_size >= (size_t)nZ * sizeof(unsigned short);
  if (useWs) {
    unsigned short* zb = (unsigned short*)d_ws;
    int nThr = nZ / 8;
    cvt_bf16_kernel<<<(nThr + 255) / 256, 256, 0, stream>>>(z, zb, nZ);
    lp_main<true><<<1024, 256, 0, stream>>>(z, zb, ei, W1, b1, W2, b2, W3, b3, out, nEdges);
  } else {
    lp_main<false><<<1024, 256, 0, stream>>>(z, nullptr, ei, W1, b1, W2, b2, W3, b3, out, nEdges);
  }
}

// Round 9
// 146.138 us; speedup vs baseline: 1.7564x; 1.7564x over previous
//
#include <hip/hip_runtime.h>
#include <hip/hip_bf16.h>

typedef __attribute__((ext_vector_type(8))) short short8;
typedef __attribute__((ext_vector_type(4))) float f32x4;

__device__ __forceinline__ unsigned short f32_bf16(float f) {
  unsigned u = __float_as_uint(f);
  u += 0x7fffu + ((u >> 16) & 1u);  // round-to-nearest-even
  return (unsigned short)(u >> 16);
}

__device__ __forceinline__ short8 cvt8(float4 v0, float4 v1) {
  short8 f;
  f[0] = (short)f32_bf16(v0.x); f[1] = (short)f32_bf16(v0.y);
  f[2] = (short)f32_bf16(v0.z); f[3] = (short)f32_bf16(v0.w);
  f[4] = (short)f32_bf16(v1.x); f[5] = (short)f32_bf16(v1.y);
  f[6] = (short)f32_bf16(v1.z); f[7] = (short)f32_bf16(v1.w);
  return f;
}

// unpack two bf16 pairs, add U+V+b, relu, repack (RNE)
__device__ __forceinline__ unsigned addrelu2(unsigned uw, unsigned vw, float blo, float bhi) {
  float ulo = __uint_as_float(uw << 16);
  float uhi = __uint_as_float(uw & 0xffff0000u);
  float vlo = __uint_as_float(vw << 16);
  float vhi = __uint_as_float(vw & 0xffff0000u);
  float slo = ulo + vlo + blo; slo = slo > 0.f ? slo : 0.f;
  float shi = uhi + vhi + bhi; shi = shi > 0.f ? shi : 0.f;
  return ((unsigned)f32_bf16(shi) << 16) | (unsigned)f32_bf16(slo);
}

// DPP row_shr:N add — lane 15 of each 16-lane row ends with the row sum.
template <int CTRL>
__device__ __forceinline__ float dpp_add(float x) {
  int y = __builtin_amdgcn_update_dpp(0, __float_as_int(x), CTRL, 0xf, 0xf, true);
  return x + __int_as_float(y);
}
__device__ __forceinline__ float row_sum16(float x) {
  x = dpp_add<0x118>(x);
  x = dpp_add<0x114>(x);
  x = dpp_add<0x112>(x);
  x = dpp_add<0x111>(x);
  return x;
}

// ---- pass 1: UV[n] = [ Z[n]·W1a , Z[n]·W1b ] in bf16 (256 B per node) ------
// Dense GEMM M=nNodes, N=128, K=128 on 16x16x32 MFMA. W1 B-fragments staged in
// LDS with the column-slot permutation slot(t, col=l15) = feature l15*8+t, so
// each lane's 8 ntile outputs are feature-contiguous -> one uint4 store/row.
// Feature n<64 -> W1 rows 0..127 (src half); n>=64 -> rows 128..255 (dst half).
__global__ __launch_bounds__(256, 2) void uv_kernel(
    const float* __restrict__ z, const float* __restrict__ W1,
    unsigned short* __restrict__ uv, int nNodes) {
  __shared__ unsigned short w1l[32 * 64 * 8];  // 32 KB
  const int tid = threadIdx.x;
  const int wv  = tid >> 6;
  const int l   = tid & 63;
  const int l15 = l & 15;
  const int q   = l >> 4;

#pragma unroll
  for (int pp = 0; pp < 8; ++pp) {
    int p = wv * 8 + pp;       // p = c*8 + t
    int c = p >> 3, t = p & 7;
    short8 f;
#pragma unroll
    for (int j = 0; j < 8; ++j) {
      int k = c * 32 + q * 8 + j;
      int n = l15 * 8 + t;
      int row = (n < 64) ? k : (k + 128);
      f[j] = (short)f32_bf16(W1[row * 64 + (n & 63)]);
    }
    *(short8*)(w1l + (p * 64 + l) * 8) = f;
  }
  __syncthreads();

  const int nTiles = (nNodes + 15) >> 4;
  const int stride = gridDim.x * 4;
  for (int tile = blockIdx.x * 4 + wv; tile < nTiles; tile += stride) {
    int node = tile * 16 + l15;
    node = node < nNodes ? node : nNodes - 1;
    const float* zr = z + (size_t)node * 128;
    short8 a[4];
#pragma unroll
    for (int c = 0; c < 4; ++c) {
      int off = c * 32 + q * 8;
      a[c] = cvt8(*(const float4*)(zr + off), *(const float4*)(zr + off + 4));
    }
    f32x4 acc[8];
#pragma unroll
    for (int t = 0; t < 8; ++t) { acc[t][0] = 0.f; acc[t][1] = 0.f; acc[t][2] = 0.f; acc[t][3] = 0.f; }
#pragma unroll
    for (int c = 0; c < 4; ++c)
#pragma unroll
      for (int t = 0; t < 8; ++t) {
        short8 wf = *(const short8*)(w1l + ((c * 8 + t) * 64 + l) * 8);
        acc[t] = __builtin_amdgcn_mfma_f32_16x16x32_bf16(a[c], wf, acc[t], 0, 0, 0);
      }
    // D[row=q*4+r][col=l15], slot(t,l15) = feature l15*8+t -> natural order
#pragma unroll
    for (int r = 0; r < 4; ++r) {
      int no = tile * 16 + q * 4 + r;
      if (no < nNodes) {
        union { unsigned short us[8]; uint4 u4; } pk;
#pragma unroll
        for (int t = 0; t < 8; ++t) pk.us[t] = f32_bf16(acc[t][r]);
        *(uint4*)(uv + (size_t)no * 128 + l15 * 8) = pk.u4;
      }
    }
  }
}

// ---- pass 2: per-edge gather UV + relu-add + layers 2,3 + sigmoid -----------
// Per edge: ONE 128 B line from UV[src] (U half) + ONE from UV[dst] (V half)
// — half of R1-R8's 512 B/edge gather. The per-lane add+relu directly yields
// the layer-2 A-fragment (a[j] = A[m=l15][k=q*8+j]) — no LDS at all, ~80 arch
// regs (way under the measured 128-arch wall), so occupancy is register-cheap.
__global__ __launch_bounds__(256, 2) void lp_edge(
    const unsigned short* __restrict__ uv, const int* __restrict__ ei,
    const float* __restrict__ b1,
    const float* __restrict__ W2, const float* __restrict__ b2,
    const float* __restrict__ W3, const float* __restrict__ b3,
    float* __restrict__ out, int nEdges) {
  const int tid = threadIdx.x;
  const int wv  = tid >> 6;
  const int l   = tid & 63;
  const int l15 = l & 15;
  const int q   = l >> 4;

  short8 w2f[2][2];
#pragma unroll
  for (int c = 0; c < 2; ++c)
#pragma unroll
    for (int t = 0; t < 2; ++t) {
      short8 f;
#pragma unroll
      for (int j = 0; j < 8; ++j)
        f[j] = (short)f32_bf16(W2[(c * 32 + q * 8 + j) * 32 + (t * 16 + l15)]);
      w2f[c][t] = f;
    }
  float bb2[2];
#pragma unroll
  for (int t = 0; t < 2; ++t) bb2[t] = b2[t * 16 + l15];
  const float w3a = W3[l15], w3b = W3[16 + l15], b3v = b3[0];
  float b1f0[8], b1f1[8];
#pragma unroll
  for (int j = 0; j < 8; ++j) { b1f0[j] = b1[q * 8 + j]; b1f1[j] = b1[32 + q * 8 + j]; }

  const int nIter = (nEdges + 15) >> 4;
  const int stride = gridDim.x * 4;
  int iter = blockIdx.x * 4 + wv;

  int cS = 0, cD = 0;
  if (iter < nIter) {
    int e = iter * 16 + l15;
    e = e < nEdges ? e : nEdges - 1;
    cS = ei[e];
    cD = ei[nEdges + e];
  }

  for (; iter < nIter; iter += stride) {
    const unsigned short* us = uv + (size_t)cS * 128;        // U half (bytes 0..127)
    const unsigned short* vd = uv + (size_t)cD * 128 + 64;   // V half (bytes 128..255)
    uint4 au0 = *(const uint4*)(us + q * 8);        // features q*8..+8
    uint4 au1 = *(const uint4*)(us + 32 + q * 8);   // features 32+q*8..+8
    uint4 av0 = *(const uint4*)(vd + q * 8);
    uint4 av1 = *(const uint4*)(vd + 32 + q * 8);

    int nit = iter + stride;
    int nS = cS, nD = cD;
    if (nit < nIter) {
      int e = nit * 16 + l15;
      e = e < nEdges ? e : nEdges - 1;
      nS = ei[e];
      nD = ei[nEdges + e];
    }

    // h1 fragments: relu(U + V + b1) — computed straight into A-frag layout
    union { unsigned u[4]; short8 s; } f0, f1;
    f0.u[0] = addrelu2(au0.x, av0.x, b1f0[0], b1f0[1]);
    f0.u[1] = addrelu2(au0.y, av0.y, b1f0[2], b1f0[3]);
    f0.u[2] = addrelu2(au0.z, av0.z, b1f0[4], b1f0[5]);
    f0.u[3] = addrelu2(au0.w, av0.w, b1f0[6], b1f0[7]);
    f1.u[0] = addrelu2(au1.x, av1.x, b1f1[0], b1f1[1]);
    f1.u[1] = addrelu2(au1.y, av1.y, b1f1[2], b1f1[3]);
    f1.u[2] = addrelu2(au1.z, av1.z, b1f1[4], b1f1[5]);
    f1.u[3] = addrelu2(au1.w, av1.w, b1f1[6], b1f1[7]);

    // layer 2: [16,64] @ [64,32] + b2
    f32x4 acc2[2];
#pragma unroll
    for (int t = 0; t < 2; ++t) {
      acc2[t][0] = bb2[t]; acc2[t][1] = bb2[t]; acc2[t][2] = bb2[t]; acc2[t][3] = bb2[t];
    }
#pragma unroll
    for (int t = 0; t < 2; ++t) {
      acc2[t] = __builtin_amdgcn_mfma_f32_16x16x32_bf16(f0.s, w2f[0][t], acc2[t], 0, 0, 0);
      acc2[t] = __builtin_amdgcn_mfma_f32_16x16x32_bf16(f1.s, w2f[1][t], acc2[t], 0, 0, 0);
    }

    // layer 3: per-lane partial, DPP row-sum
    float p[4];
#pragma unroll
    for (int r = 0; r < 4; ++r) {
      float h0 = acc2[0][r]; h0 = h0 > 0.f ? h0 : 0.f;
      float h1v = acc2[1][r]; h1v = h1v > 0.f ? h1v : 0.f;
      p[r] = row_sum16(h0 * w3a + h1v * w3b);
    }

    if (l15 == 15) {
      int eb = iter * 16 + q * 4;
      float4 o;
      o.x = 1.f / (1.f + __expf(-(p[0] + b3v)));
      o.y = 1.f / (1.f + __expf(-(p[1] + b3v)));
      o.z = 1.f / (1.f + __expf(-(p[2] + b3v)));
      o.w = 1.f / (1.f + __expf(-(p[3] + b3v)));
      if (eb + 3 < nEdges) {
        *(float4*)(out + eb) = o;
      } else {
        if (eb < nEdges)     out[eb]     = o.x;
        if (eb + 1 < nEdges) out[eb + 1] = o.y;
        if (eb + 2 < nEdges) out[eb + 2] = o.z;
      }
    }

    cS = nS; cD = nD;
  }
}

// ---- correctness-only fallback (ws too small; never expected) ---------------
__global__ void lp_naive(const float* __restrict__ z, const int* __restrict__ ei,
                         const float* __restrict__ W1, const float* __restrict__ b1,
                         const float* __restrict__ W2, const float* __restrict__ b2,
                         const float* __restrict__ W3, const float* __restrict__ b3,
                         float* __restrict__ out, int nEdges) {
  int e = blockIdx.x * 256 + threadIdx.x;
  if (e >= nEdges) return;
  int s = ei[e], d = ei[nEdges + e];
  float h1[64], h2[32];
  for (int k = 0; k < 64; ++k) {
    float a = b1[k];
    for (int i = 0; i < 128; ++i) a += z[(size_t)s * 128 + i] * W1[i * 64 + k];
    for (int i = 0; i < 128; ++i) a += z[(size_t)d * 128 + i] * W1[(128 + i) * 64 + k];
    h1[k] = a > 0.f ? a : 0.f;
  }
  for (int k = 0; k < 32; ++k) {
    float a = b2[k];
    for (int i = 0; i < 64; ++i) a += h1[i] * W2[i * 32 + k];
    h2[k] = a > 0.f ? a : 0.f;
  }
  float lg = b3[0];
  for (int i = 0; i < 32; ++i) lg += h2[i] * W3[i];
  out[e] = 1.f / (1.f + __expf(-lg));
}

extern "C" void kernel_launch(void* const* d_in, const int* in_sizes, int n_in,
                              void* d_out, int out_size, void* d_ws, size_t ws_size,
                              hipStream_t stream) {
  const float* z  = (const float*)d_in[0];
  const int* ei   = (const int*)d_in[1];
  const float* W1 = (const float*)d_in[2];
  const float* b1 = (const float*)d_in[3];
  const float* W2 = (const float*)d_in[4];
  const float* b2 = (const float*)d_in[5];
  const float* W3 = (const float*)d_in[6];
  const float* b3 = (const float*)d_in[7];
  float* out = (float*)d_out;

  const int nZ = in_sizes[0];
  const int nNodes = nZ / 128;
  const int nEdges = in_sizes[1] / 2;

  if (ws_size >= (size_t)nNodes * 128 * sizeof(unsigned short)) {
    unsigned short* uvp = (unsigned short*)d_ws;
    uv_kernel<<<1024, 256, 0, stream>>>(z, W1, uvp, nNodes);
    lp_edge<<<1024, 256, 0, stream>>>(uvp, ei, b1, W2, b2, W3, b3, out, nEdges);
  } else {
    lp_naive<<<(nEdges + 255) / 256, 256, 0, stream>>>(z, ei, W1, b1, W2, b2, W3, b3, out, nEdges);
  }
}